// Round 4
// baseline (240.569 us; speedup 1.0000x reference)
//
#include <hip/hip_runtime.h>

typedef _Float16 half_t;
typedef _Float16 v8h __attribute__((ext_vector_type(8)));
typedef float v4f __attribute__((ext_vector_type(4)));

#define XTP 40   // xt LDS row pitch (halves): 32 data + 8 pad
#define HP  72   // h  LDS row pitch (halves): 64 data + 8 pad

// ===== merged W prep: W (128,K) f32 -> f16, per-16o-group streams =====
// Layout: w[o/16][k8][o%16][8]  (k8 = k/8). A wave owning o-group g reads a fully
// CONTIGUOUS byte stream: step s (K=32 chunk) = 1KB at g*(K*32B) + s*1024.
// Read-coalesced mapping: lane-consecutive threads take consecutive k8 of one o-row.
__global__ __launch_bounds__(256) void prep_w_all(const float* __restrict__ W0,
                                                  const float* __restrict__ W1,
                                                  const float* __restrict__ W2,
                                                  half_t* __restrict__ w0h,
                                                  half_t* __restrict__ w1h,
                                                  half_t* __restrict__ w2h) {
  int i = blockIdx.x * 256 + threadIdx.x;         // 0..81919 (wave-uniform segments)
  const float* src; half_t* dst; int ktot; int ksh; int j;
  if (i < 16384)      { src = W0; dst = w0h; ktot = 1024; ksh = 7; j = i; }
  else if (i < 49152) { src = W1; dst = w1h; ktot = 2048; ksh = 8; j = i - 16384; }
  else                { src = W2; dst = w2h; ktot = 2048; ksh = 8; j = i - 49152; }
  int o = j >> ksh, k8 = j & ((1 << ksh) - 1);
  const float* s = src + (size_t)o * ktot + k8 * 8;
  float4 f0 = *(const float4*)s;
  float4 f1 = *(const float4*)(s + 4);
  union { half_t h[8]; uint4 u; } pk;
  pk.h[0] = (half_t)f0.x; pk.h[1] = (half_t)f0.y; pk.h[2] = (half_t)f0.z; pk.h[3] = (half_t)f0.w;
  pk.h[4] = (half_t)f1.x; pk.h[5] = (half_t)f1.y; pk.h[6] = (half_t)f1.z; pk.h[7] = (half_t)f1.w;
  size_t di = ((size_t)(((o >> 4) << ksh) + k8) * 128) + (size_t)(o & 15) * 8;  // halves
  *(uint4*)(dst + di) = pk.u;
}

// ============ one CIN layer: Y = relu(W @ Z + b), Z built on the fly ============
// 8-way M split, 1-way N split: wave wv owns o in [wv*16, wv*16+16), ALL 64 columns
// (4 batch x 16 e). W fragment consumed by exactly one wave -> no LDS for W:
// stream W global->VGPR, one coalesced 1KB global_load_dwordx4 per K=32 step,
// depth-2 register prefetch (compiler inserts counted vmcnt). NO per-step barriers.
// A-frag (16x16x32 f16): o = lane&15, k = (lane>>4)*8 + elem  -> matches prep layout.
template <int G, int KTOT, int KEEP, int OUT_BASE, bool H_OUT, bool H_IS_X>
__device__ __forceinline__ void layer(const half_t* __restrict__ wgt,
                                      const float* __restrict__ bias,
                                      const half_t* __restrict__ xt_lds,
                                      half_t* __restrict__ h_lds,
                                      float* __restrict__ out,
                                      size_t b0, int tid) {
  constexpr int SPO  = (G == 64) ? 16 : 8;  // steps per f-octet
  constexpr int NSEL = (G == 64) ? 2 : 1;
  const int lane = tid & 63;
  const int wv = tid >> 6;                  // m-tile index 0..7 (o base = wv*16)
  const int e16 = lane & 15;                // e (and A-frag o-row)
  const int kq = lane >> 4;                 // k-quad

  __syncthreads();   // entry: xt staging / previous layer's h_lds writes visible

  int lrow[4];
#pragma unroll
  for (int ni = 0; ni < 4; ++ni) lrow[ni] = ni * 16 + e16;   // batch ni, embed e16

  // ---- h fragments: register-resident for the whole K-loop ----
  const half_t* hb = H_IS_X ? xt_lds : h_lds;
  const int hpitch = H_IS_X ? XTP : HP;
  v8h hreg[4][NSEL];
#pragma unroll
  for (int ni = 0; ni < 4; ++ni)
#pragma unroll
    for (int s = 0; s < NSEL; ++s)
      hreg[ni][s] = *(const v8h*)(hb + lrow[ni] * hpitch + s * 32 + kq * 8);

  __syncthreads();   // all waves snapshotted h before anyone's epilogue overwrites it

  // ---- W stream: wave-contiguous; prologue loads steps 0,1 ----
  const half_t* wl = wgt + (size_t)wv * (KTOT * 16) + kq * 128 + e16 * 8;
  v8h a_cur = *(const v8h*)(wl);
  v8h a_nxt = *(const v8h*)(wl + 512);
  wl += 1024;

  v4f acc[4] = {};
  v8h xv[4];

  auto step = [&](v8h a, int t) {
    const int j   = (G == 64) ? (t >> 1) : t;
    const int sel = (G == 64) ? (t & 1) : 0;
#pragma unroll
    for (int ni = 0; ni < 4; ++ni) {
      v8h bfr = hreg[ni][sel] * xv[ni][j];
      acc[ni] = __builtin_amdgcn_mfma_f32_16x16x32_f16(a, bfr, acc[ni], 0, 0, 0);
    }
  };

  // ---- octets 0..2 (full, with depth-2 prefetch) ----
#pragma unroll 1
  for (int oct = 0; oct < 3; ++oct) {
#pragma unroll
    for (int ni = 0; ni < 4; ++ni)
      xv[ni] = *(const v8h*)(xt_lds + lrow[ni] * XTP + oct * 8);
#pragma unroll
    for (int t = 0; t < SPO; t += 2) {
      v8h a0 = a_cur; a_cur = *(const v8h*)(wl);          // prefetch step s+2
      step(a0, t);
      v8h a1 = a_nxt; a_nxt = *(const v8h*)(wl + 512);    // prefetch step s+3
      wl += 1024;
      step(a1, t + 1);
    }
  }

  // ---- octet 3 (prefetch stops 2 steps early; tail uses last two regs) ----
  {
#pragma unroll
    for (int ni = 0; ni < 4; ++ni)
      xv[ni] = *(const v8h*)(xt_lds + lrow[ni] * XTP + 3 * 8);
#pragma unroll
    for (int t = 0; t < SPO - 2; t += 2) {
      v8h a0 = a_cur; a_cur = *(const v8h*)(wl);
      step(a0, t);
      v8h a1 = a_nxt; a_nxt = *(const v8h*)(wl + 512);
      wl += 1024;
      step(a1, t + 1);
    }
    step(a_cur, SPO - 2);
    step(a_nxt, SPO - 1);
  }

  // ---- epilogue: bias + relu; wv>=4 -> h_lds (B-layout); o<KEEP -> sum_e -> out ----
  // C/D (16x16x32): col = lane&15 = e16, row = kq*4 + r  ->  o = wv*16 + kq*4 + r.
  // h_lds writes race-free: post-hreg barrier above guarantees all waves read old h.
  const int o_base = wv * 16 + kq * 4;
  float4 b4 = *(const float4*)(bias + o_base);
#pragma unroll
  for (int ni = 0; ni < 4; ++ni) {
    float v[4];
#pragma unroll
    for (int r = 0; r < 4; ++r)
      v[r] = fmaxf(acc[ni][r] + (&b4.x)[r], 0.0f);
    if (H_OUT && wv >= 4) {                     // wave-uniform
      union { half_t h[4]; uint2 u; } pk;
#pragma unroll
      for (int r = 0; r < 4; ++r) pk.h[r] = (half_t)v[r];
      *(uint2*)(h_lds + lrow[ni] * HP + (o_base - 64)) = pk.u;
    }
    if (wv * 16 < KEEP) {                       // wave-uniform
#pragma unroll
      for (int r = 0; r < 4; ++r) {
        float sv = v[r];
        sv += __shfl_xor(sv, 1);
        sv += __shfl_xor(sv, 2);
        sv += __shfl_xor(sv, 4);
        sv += __shfl_xor(sv, 8);                // sum over e (16-lane group)
        if (e16 == 0) out[(b0 + ni) * 256 + OUT_BASE + o_base + r] = sv;
      }
    }
  }
}

// ============ fused CIN: all 3 layers, one block = 4 batch elements ============
// 512 thr (8 waves), grid 1024. LDS only 14.3KB (xt 5KB + h 9.2KB) -> occupancy is
// VGPR-bound: launch_bounds(512,6) caps at 85 regs -> 3 blocks/CU = 24 waves/CU
// (6/SIMD), 1.5x the old ring-buffer version, and waves are barrier-free in the K-loop.
__global__ __launch_bounds__(512, 6) void cin_fused(const float* __restrict__ x,
                                                    const half_t* __restrict__ w0h,
                                                    const half_t* __restrict__ w1h,
                                                    const half_t* __restrict__ w2h,
                                                    const float* __restrict__ b0p,
                                                    const float* __restrict__ b1p,
                                                    const float* __restrict__ b2p,
                                                    float* __restrict__ out) {
  __shared__ __align__(16) half_t xt_lds[64 * XTP];
  __shared__ __align__(16) half_t h_lds[64 * HP];

  const int tid = threadIdx.x;
  const size_t b0 = (size_t)blockIdx.x * 4;

  // ---- stage xt from x f32 (b,f,e) -> LDS (b,e) rows x 32 f, f16 ----
  {
    int idx = tid * 4;                          // 0..2047 by 4 (e%4==0 within one f,b)
    float4 v = *(const float4*)(x + b0 * 512 + idx);
    int e = idx & 15, f = (idx >> 4) & 31, b = idx >> 9;
    half_t* d = xt_lds + (b * 16 + e) * XTP + f;
    d[0 * XTP] = (half_t)v.x;
    d[1 * XTP] = (half_t)v.y;
    d[2 * XTP] = (half_t)v.z;
    d[3 * XTP] = (half_t)v.w;
  }

  // layer 0: G=32 (h = x0), keep o<64 -> out ch [0,64), o>=64 -> h_lds
  layer<32, 1024, 64, 0, true, true>(w0h, b0p, xt_lds, h_lds, out, b0, tid);
  // layer 1: G=64, keep o<64 -> out ch [64,128), o>=64 -> h_lds (overwrite)
  layer<64, 2048, 64, 64, true, false>(w1h, b1p, xt_lds, h_lds, out, b0, tid);
  // layer 2: G=64, keep all 128 -> out ch [128,256)
  layer<64, 2048, 128, 128, false, false>(w2h, b2p, xt_lds, h_lds, out, b0, tid);
}

extern "C" void kernel_launch(void* const* d_in, const int* in_sizes, int n_in,
                              void* d_out, int out_size, void* d_ws, size_t ws_size,
                              hipStream_t stream) {
  const float* x  = (const float*)d_in[0];
  const float* W0 = (const float*)d_in[1];
  const float* b0 = (const float*)d_in[2];
  const float* W1 = (const float*)d_in[3];
  const float* b1 = (const float*)d_in[4];
  const float* W2 = (const float*)d_in[5];
  const float* b2 = (const float*)d_in[6];
  float* out = (float*)d_out;
  char* ws = (char*)d_ws;

  half_t* w0h = (half_t*)(ws);                       // 256 KB
  half_t* w1h = (half_t*)(ws + (256u << 10));        // 512 KB
  half_t* w2h = (half_t*)(ws + (768u << 10));        // 512 KB

  prep_w_all<<<320, 256, 0, stream>>>(W0, W1, W2, w0h, w1h, w2h);
  cin_fused<<<1024, 512, 0, stream>>>(x, w0h, w1h, w2h, b0, b1, b2, out);
}

// Round 5
// 162.874 us; speedup vs baseline: 1.4770x; 1.4770x over previous
//
#include <hip/hip_runtime.h>

typedef _Float16 half_t;
typedef _Float16 v8h __attribute__((ext_vector_type(8)));
typedef float v4f __attribute__((ext_vector_type(4)));

#define XTP 40   // xt LDS row pitch (halves): 32 data + 8 pad
#define HP  72   // h  LDS row pitch (halves): 64 data + 8 pad

// ===== merged W prep: W (128,K) f32 -> f16, per-16o-group streams =====
// Layout: w[o/16][k8][o%16][8]  (k8 = k/8). A wave owning o-group g reads a fully
// CONTIGUOUS byte stream: step s (K=32 chunk) = 1KB at g*(K*32B) + s*1024.
// Read-coalesced mapping: lane-consecutive threads take consecutive k8 of one o-row.
__global__ __launch_bounds__(256) void prep_w_all(const float* __restrict__ W0,
                                                  const float* __restrict__ W1,
                                                  const float* __restrict__ W2,
                                                  half_t* __restrict__ w0h,
                                                  half_t* __restrict__ w1h,
                                                  half_t* __restrict__ w2h) {
  int i = blockIdx.x * 256 + threadIdx.x;         // 0..81919 (wave-uniform segments)
  const float* src; half_t* dst; int ktot; int ksh; int j;
  if (i < 16384)      { src = W0; dst = w0h; ktot = 1024; ksh = 7; j = i; }
  else if (i < 49152) { src = W1; dst = w1h; ktot = 2048; ksh = 8; j = i - 16384; }
  else                { src = W2; dst = w2h; ktot = 2048; ksh = 8; j = i - 49152; }
  int o = j >> ksh, k8 = j & ((1 << ksh) - 1);
  const float* s = src + (size_t)o * ktot + k8 * 8;
  float4 f0 = *(const float4*)s;
  float4 f1 = *(const float4*)(s + 4);
  union { half_t h[8]; uint4 u; } pk;
  pk.h[0] = (half_t)f0.x; pk.h[1] = (half_t)f0.y; pk.h[2] = (half_t)f0.z; pk.h[3] = (half_t)f0.w;
  pk.h[4] = (half_t)f1.x; pk.h[5] = (half_t)f1.y; pk.h[6] = (half_t)f1.z; pk.h[7] = (half_t)f1.w;
  size_t di = ((size_t)(((o >> 4) << ksh) + k8) * 128) + (size_t)(o & 15) * 8;  // halves
  *(uint4*)(dst + di) = pk.u;
}

// ============ one CIN layer: Y = relu(W @ Z + b), Z built on the fly ============
// 8-way M split, 1-way N split: wave wv owns o in [wv*16, wv*16+16), ALL 64 columns
// (4 batch x 16 e). W fragment consumed by exactly one wave -> no LDS for W:
// stream W global->VGPR, one coalesced 1KB global_load_dwordx4 per K=32 step,
// depth-2 register prefetch (compiler inserts counted vmcnt). NO per-step barriers.
// A-frag (16x16x32 f16): o = lane&15, k = (lane>>4)*8 + elem  -> matches prep layout.
template <int G, int KTOT, int KEEP, int OUT_BASE, bool H_OUT, bool H_IS_X>
__device__ __forceinline__ void layer(const half_t* __restrict__ wgt,
                                      const float* __restrict__ bias,
                                      const half_t* __restrict__ xt_lds,
                                      half_t* __restrict__ h_lds,
                                      float* __restrict__ out,
                                      size_t b0, int tid) {
  constexpr int SPO  = (G == 64) ? 16 : 8;  // steps per f-octet
  constexpr int NSEL = (G == 64) ? 2 : 1;
  const int lane = tid & 63;
  const int wv = tid >> 6;                  // m-tile index 0..7 (o base = wv*16)
  const int e16 = lane & 15;                // e (and A-frag o-row)
  const int kq = lane >> 4;                 // k-quad

  __syncthreads();   // entry: xt staging / previous layer's h_lds writes visible

  int lrow[4];
#pragma unroll
  for (int ni = 0; ni < 4; ++ni) lrow[ni] = ni * 16 + e16;   // batch ni, embed e16

  // ---- h fragments: register-resident for the whole K-loop ----
  const half_t* hb = H_IS_X ? xt_lds : h_lds;
  const int hpitch = H_IS_X ? XTP : HP;
  v8h hreg[4][NSEL];
#pragma unroll
  for (int ni = 0; ni < 4; ++ni)
#pragma unroll
    for (int s = 0; s < NSEL; ++s)
      hreg[ni][s] = *(const v8h*)(hb + lrow[ni] * hpitch + s * 32 + kq * 8);

  __syncthreads();   // all waves snapshotted h before anyone's epilogue overwrites it

  // ---- W stream: wave-contiguous; prologue loads steps 0,1 ----
  const half_t* wl = wgt + (size_t)wv * (KTOT * 16) + kq * 128 + e16 * 8;
  v8h a_cur = *(const v8h*)(wl);
  v8h a_nxt = *(const v8h*)(wl + 512);
  wl += 1024;

  v4f acc[4] = {};
  v8h xv[4];

  auto step = [&](v8h a, int t) {
    const int j   = (G == 64) ? (t >> 1) : t;
    const int sel = (G == 64) ? (t & 1) : 0;
#pragma unroll
    for (int ni = 0; ni < 4; ++ni) {
      v8h bfr = hreg[ni][sel] * xv[ni][j];
      acc[ni] = __builtin_amdgcn_mfma_f32_16x16x32_f16(a, bfr, acc[ni], 0, 0, 0);
    }
  };

  // ---- octets 0..2 (full, with depth-2 prefetch) ----
#pragma unroll 1
  for (int oct = 0; oct < 3; ++oct) {
#pragma unroll
    for (int ni = 0; ni < 4; ++ni)
      xv[ni] = *(const v8h*)(xt_lds + lrow[ni] * XTP + oct * 8);
#pragma unroll
    for (int t = 0; t < SPO; t += 2) {
      v8h a0 = a_cur; a_cur = *(const v8h*)(wl);          // prefetch step s+2
      step(a0, t);
      v8h a1 = a_nxt; a_nxt = *(const v8h*)(wl + 512);    // prefetch step s+3
      wl += 1024;
      step(a1, t + 1);
    }
  }

  // ---- octet 3 (prefetch stops 2 steps early; tail uses last two regs) ----
  {
#pragma unroll
    for (int ni = 0; ni < 4; ++ni)
      xv[ni] = *(const v8h*)(xt_lds + lrow[ni] * XTP + 3 * 8);
#pragma unroll
    for (int t = 0; t < SPO - 2; t += 2) {
      v8h a0 = a_cur; a_cur = *(const v8h*)(wl);
      step(a0, t);
      v8h a1 = a_nxt; a_nxt = *(const v8h*)(wl + 512);
      wl += 1024;
      step(a1, t + 1);
    }
    step(a_cur, SPO - 2);
    step(a_nxt, SPO - 1);
  }

  // ---- epilogue: bias + relu; wv>=4 -> h_lds (B-layout); o<KEEP -> sum_e -> out ----
  // C/D (16x16x32): col = lane&15 = e16, row = kq*4 + r  ->  o = wv*16 + kq*4 + r.
  // h_lds writes race-free: post-hreg barrier above guarantees all waves read old h.
  const int o_base = wv * 16 + kq * 4;
  float4 b4 = *(const float4*)(bias + o_base);
#pragma unroll
  for (int ni = 0; ni < 4; ++ni) {
    float v[4];
#pragma unroll
    for (int r = 0; r < 4; ++r)
      v[r] = fmaxf(acc[ni][r] + (&b4.x)[r], 0.0f);
    if (H_OUT && wv >= 4) {                     // wave-uniform
      union { half_t h[4]; uint2 u; } pk;
#pragma unroll
      for (int r = 0; r < 4; ++r) pk.h[r] = (half_t)v[r];
      *(uint2*)(h_lds + lrow[ni] * HP + (o_base - 64)) = pk.u;
    }
    if (wv * 16 < KEEP) {                       // wave-uniform
#pragma unroll
      for (int r = 0; r < 4; ++r) {
        float sv = v[r];
        sv += __shfl_xor(sv, 1);
        sv += __shfl_xor(sv, 2);
        sv += __shfl_xor(sv, 4);
        sv += __shfl_xor(sv, 8);                // sum over e (16-lane group)
        if (e16 == 0) out[(b0 + ni) * 256 + OUT_BASE + o_base + r] = sv;
      }
    }
  }
}

// ============ fused CIN: all 3 layers, one block = 4 batch elements ============
// 512 thr (8 waves), grid 1024. launch_bounds(512,4): 128-VGPR cap -- live set is
// ~100 regs (hreg 32 + xv 16 + acc 16 + prefetch 8 + addr), so NO spill (the (512,6)
// 85-reg cap caused a 320MB scratch catastrophe). 2 blocks/CU = 4 waves/SIMD, but
// unlike the ring version the K-loop has zero barriers: waves fully decoupled.
__global__ __launch_bounds__(512, 4) void cin_fused(const float* __restrict__ x,
                                                    const half_t* __restrict__ w0h,
                                                    const half_t* __restrict__ w1h,
                                                    const half_t* __restrict__ w2h,
                                                    const float* __restrict__ b0p,
                                                    const float* __restrict__ b1p,
                                                    const float* __restrict__ b2p,
                                                    float* __restrict__ out) {
  __shared__ __align__(16) half_t xt_lds[64 * XTP];
  __shared__ __align__(16) half_t h_lds[64 * HP];

  const int tid = threadIdx.x;
  const size_t b0 = (size_t)blockIdx.x * 4;

  // ---- stage xt from x f32 (b,f,e) -> LDS (b,e) rows x 32 f, f16 ----
  {
    int idx = tid * 4;                          // 0..2047 by 4 (e%4==0 within one f,b)
    float4 v = *(const float4*)(x + b0 * 512 + idx);
    int e = idx & 15, f = (idx >> 4) & 31, b = idx >> 9;
    half_t* d = xt_lds + (b * 16 + e) * XTP + f;
    d[0 * XTP] = (half_t)v.x;
    d[1 * XTP] = (half_t)v.y;
    d[2 * XTP] = (half_t)v.z;
    d[3 * XTP] = (half_t)v.w;
  }

  // layer 0: G=32 (h = x0), keep o<64 -> out ch [0,64), o>=64 -> h_lds
  layer<32, 1024, 64, 0, true, true>(w0h, b0p, xt_lds, h_lds, out, b0, tid);
  // layer 1: G=64, keep o<64 -> out ch [64,128), o>=64 -> h_lds (overwrite)
  layer<64, 2048, 64, 64, true, false>(w1h, b1p, xt_lds, h_lds, out, b0, tid);
  // layer 2: G=64, keep all 128 -> out ch [128,256)
  layer<64, 2048, 128, 128, false, false>(w2h, b2p, xt_lds, h_lds, out, b0, tid);
}

extern "C" void kernel_launch(void* const* d_in, const int* in_sizes, int n_in,
                              void* d_out, int out_size, void* d_ws, size_t ws_size,
                              hipStream_t stream) {
  const float* x  = (const float*)d_in[0];
  const float* W0 = (const float*)d_in[1];
  const float* b0 = (const float*)d_in[2];
  const float* W1 = (const float*)d_in[3];
  const float* b1 = (const float*)d_in[4];
  const float* W2 = (const float*)d_in[5];
  const float* b2 = (const float*)d_in[6];
  float* out = (float*)d_out;
  char* ws = (char*)d_ws;

  half_t* w0h = (half_t*)(ws);                       // 256 KB
  half_t* w1h = (half_t*)(ws + (256u << 10));        // 512 KB
  half_t* w2h = (half_t*)(ws + (768u << 10));        // 512 KB

  prep_w_all<<<320, 256, 0, stream>>>(W0, W1, W2, w0h, w1h, w2h);
  cin_fused<<<1024, 512, 0, stream>>>(x, w0h, w1h, w2h, b0, b1, b2, out);
}